// Round 8
// baseline (533.891 us; speedup 1.0000x reference)
//
#include <hip/hip_runtime.h>
#include <hip/hip_bf16.h>
#include <cstdint>
#include <cstddef>

// ---------- types ----------
typedef __bf16 bf16_t;
typedef __bf16 bf16x8 __attribute__((ext_vector_type(8)));
typedef __bf16 bf16x4 __attribute__((ext_vector_type(4)));
typedef float  f32x4  __attribute__((ext_vector_type(4)));

#define DIM    1024
#define NCOEF  8
#define KTOT   (DIM + DIM * NCOEF)   // 9216
#define NKNOT  12
#define BATCH  8192
#define LN_EPS 1e-5f

// ---------- device helpers ----------
__device__ __forceinline__ float gelu_exact(float x) {
    return 0.5f * x * (1.0f + erff(x * 0.70710678118654752440f));
}

__device__ __forceinline__ void gl_lds16(const void* g, void* l) {
    __builtin_amdgcn_global_load_lds(
        (const __attribute__((address_space(1))) unsigned int*)(uintptr_t)g,
        (__attribute__((address_space(3))) unsigned int*)(uintptr_t)l, 16, 0, 0);
}

__device__ __forceinline__ uint64_t pack4bf(float a, float b, float c, float d) {
    union { bf16_t h[4]; uint64_t q; } u;
    u.h[0] = (bf16_t)a; u.h[1] = (bf16_t)b; u.h[2] = (bf16_t)c; u.h[3] = (bf16_t)d;
    return u.q;
}

// Uniform cubic B-spline: 8 bf16 bases of one feature as 16 bytes (lo,hi).
__device__ __forceinline__ void spline8(float x, float g0, float invh,
                                        uint64_t& lo, uint64_t& hi) {
    float u = (x - g0) * invh;
    float jf = floorf(u);
    int j = (int)jf;
    float f = u - jf;
    float f2 = f * f, f3 = f2 * f;
    float om = 1.0f - f, om2 = om * om;
    float w0 = om2 * om * (1.0f / 6.0f);
    float w3 = f3 * (1.0f / 6.0f);
    float w1 = fmaf(0.5f, f3, 2.0f / 3.0f) - f2;
    float w2 = 1.0f - w0 - w1 - w3;
    uint64_t W64 = pack4bf(w0, w1, w2, w3);
    if (!(u >= 0.0f && u < 11.0f)) W64 = 0;
    int sh = (j - 3) * 16;
    if (sh >= 0) {
        int s = sh & 63;
        uint64_t loW = W64 << s;
        uint64_t hiW = s ? (W64 >> (64 - s)) : 0ull;
        lo = (sh < 64) ? loW : 0ull;
        hi = (sh < 64) ? hiW : loW;
    } else {
        lo = W64 >> (-sh);
        hi = 0ull;
    }
}

// ---------- W pack: [base_w | spline_w] f32 -> bf16, K-packed ----------
__global__ void pack_w(const float* __restrict__ bw, const float* __restrict__ sw,
                       bf16_t* __restrict__ W) {
    int idx = blockIdx.x * 256 + threadIdx.x;      // (layer,o,j)
    bf16_t* wrow = W + (size_t)(idx >> 10) * KTOT;
    int j = idx & 1023;
    wrow[j] = (bf16_t)bw[idx];
    const float4* sp = (const float4*)(sw + (size_t)idx * NCOEF);
    float4 s0 = sp[0], s1 = sp[1];
    bf16x8 v;
    v[0] = (bf16_t)s0.x; v[1] = (bf16_t)s0.y; v[2] = (bf16_t)s0.z; v[3] = (bf16_t)s0.w;
    v[4] = (bf16_t)s1.x; v[5] = (bf16_t)s1.y; v[6] = (bf16_t)s1.z; v[7] = (bf16_t)s1.w;
    *(bf16x8*)(wrow + DIM + j * NCOEF) = v;
}

// ---------- layer-0 A build ----------
__global__ void prep_A(const float* __restrict__ x, bf16_t* __restrict__ A,
                       const float* __restrict__ gp, int R) {
    const int t = threadIdx.x;
    const float g0 = gp[0];
    const float invh = 1.0f / (gp[1] - gp[0]);
    for (int row = blockIdx.x; row < R; row += gridDim.x) {
        f32x4 v = *(const f32x4*)(x + (size_t)row * DIM + t * 4);
        bf16_t* Ar = A + (size_t)row * KTOT;
        bf16x4 ge;
#pragma unroll
        for (int k = 0; k < 4; k++) ge[k] = (bf16_t)gelu_exact(v[k]);
        *(bf16x4*)(Ar + t * 4) = ge;
#pragma unroll
        for (int k = 0; k < 4; k++) {
            uint64_t lo, hi;
            union { uint64_t u[2]; uint4 q; } o;
            spline8(v[k], g0, invh, lo, hi);
            o.u[0] = lo; o.u[1] = hi;
            *(uint4*)(Ar + DIM + (t * 4 + k) * NCOEF) = o.q;
        }
    }
}

// =====================================================================
// 8-phase GEMM v2: one barrier/phase, early-issued read batches.
// BM=BN=256, BK=64, 8 waves (2Mx4N, 128x64 each), dbuf by tile parity.
// Phase p body: STG(p); BAR; [reads in-phase if gated tile] LGKM; MFMA
// (one C-quadrant); [gate]; [early reads for p+1]; -> next phase's BAR.
// Publishing rule: a tile is readable only after (every wave's vmcnt
// gate) THEN a barrier. Gated 12-read batches (new tile) stay in-phase
// split by lgkmcnt(4); Bc1(4)/Ar1(8) batches are issued one phase early
// and drain across the barrier under the neighbor MFMA cluster.
// Stage rota (audited vs pending-read batches + prior-occupant reads):
//  ph1: A(T+1)h0,h1 | ph2: B(T+1)h1 | ph4: B(T+2)h0; GATE vmcnt(2)
//  ph5: A(T+2)h0,h1 | ph6: B(T+2)h1 | ph8: B(T+3)h0; GATE vmcnt(2)
// Gate counts hand-verified (10->2 at ph4, 8->2 at ph8; tail 8->0).
// =====================================================================

#define STR2(x) #x
#define GATEV(N) asm volatile("s_waitcnt vmcnt(" STR2(N) ")" ::: "memory");
#define LGKM(N)  asm volatile("s_waitcnt lgkmcnt(" STR2(N) ")" ::: "memory");
#define BAR() { __builtin_amdgcn_s_barrier(); asm volatile("" ::: "memory"); }
#define SCH0 __builtin_amdgcn_sched_barrier(0);
#define SP1 __builtin_amdgcn_s_setprio(1);
#define SP0 __builtin_amdgcn_s_setprio(0);

#define RD_A_LO(DST, BO, G) { \
    const bf16_t* p_ = ldsA + (BO) + aOffBase + (G) * 2048; \
    DST[0][0] = *(const bf16x8*)(p_);        DST[1][0] = *(const bf16x8*)(p_ + 512); \
    DST[0][1] = *(const bf16x8*)(p_ + 4096); DST[1][1] = *(const bf16x8*)(p_ + 4608); }

#define RD_A_HI(DST, BO, G) { \
    const bf16_t* p_ = ldsA + (BO) + aOffBase + (G) * 2048; \
    DST[2][0] = *(const bf16x8*)(p_ + 1024); DST[3][0] = *(const bf16x8*)(p_ + 1536); \
    DST[2][1] = *(const bf16x8*)(p_ + 5120); DST[3][1] = *(const bf16x8*)(p_ + 5632); }

#define RD_B(DST, BO, CG) { \
    const bf16_t* p_ = ldsB + (BO) + bOffBase + (CG) * 1024; \
    DST[0][0] = *(const bf16x8*)(p_);        DST[1][0] = *(const bf16x8*)(p_ + 512); \
    DST[0][1] = *(const bf16x8*)(p_ + 4096); DST[1][1] = *(const bf16x8*)(p_ + 4608); }

#define STG_A(TILE, HALF) { \
    const bf16_t* s_ = AgS + (size_t)(HALF) * (128 * (size_t)KTOT) + (size_t)(TILE) * 64; \
    bf16_t* d_ = ldsA + (((TILE) & 1) * 16384) + (HALF) * 8192 + tid * 8; \
    gl_lds16(s_, d_); gl_lds16(s_ + 32, d_ + 4096); }

#define STG_B(TILE, HALF) { \
    const bf16_t* s_ = BgS + (size_t)(HALF) * (128 * (size_t)KTOT) + (size_t)(TILE) * 64; \
    bf16_t* d_ = ldsB + (((TILE) & 1) * 16384) + (HALF) * 8192 + tid * 8; \
    gl_lds16(s_, d_); gl_lds16(s_ + 32, d_ + 4096); }

#define MFQ_HALF(G, CG, AS, BS, F0) { \
    _Pragma("unroll") \
    for (int fr_ = (F0); fr_ < (F0) + 2; fr_++) \
    _Pragma("unroll") \
    for (int ks_ = 0; ks_ < 2; ks_++) \
    _Pragma("unroll") \
    for (int cf_ = 0; cf_ < 2; cf_++) \
        acc[(G) * 4 + fr_][(CG) * 2 + cf_] = __builtin_amdgcn_mfma_f32_16x16x32_bf16( \
            AS[fr_][ks_], BS[cf_][ks_], acc[(G) * 4 + fr_][(CG) * 2 + cf_], 0, 0, 0); }

#define MFQ_FULL(G, CG, AS, BS) MFQ_HALF(G, CG, AS, BS, 0) MFQ_HALF(G, CG, AS, BS, 2)

// gated-tile phase: in-phase 12 reads split by counted lgkm
#define PH_HEAVY(STGS, BO, RDTAIL) \
    STGS \
    BAR() \
    RD_B(Bc0, BO, 0) \
    RD_A_LO(Ar0, BO, 0) \
    SCH0 \
    RD_A_HI(Ar0, BO, 0) \
    LGKM(4) SCH0 \
    SP1 MFQ_HALF(0, 0, Ar0, Bc0, 0) SP0 \
    LGKM(0) SCH0 \
    SP1 MFQ_HALF(0, 0, Ar0, Bc0, 2) SP0 \
    RDTAIL

#define PH_STD(STGS, MF, TAIL) \
    STGS \
    BAR() \
    LGKM(0) SCH0 \
    SP1 MF SP0 \
    TAIL

#define ITER8(T, SF, G4S, G8S) { \
    /* ph1: tile T q(0,0); stage A(T+1) both halves; tail-RD Bc1 */ \
    PH_HEAVY({ STG_A((T) + 1, 0) STG_A((T) + 1, 1) }, 0, RD_B(Bc1, 0, 1)) \
    /* ph2: q(0,1); stage B(T+1)h1; tail-RD Ar1 */ \
    PH_STD({ STG_B((T) + 1, 1) }, MFQ_FULL(0, 1, Ar0, Bc1), \
           RD_A_LO(Ar1, 0, 1) RD_A_HI(Ar1, 0, 1)) \
    /* ph3: q(1,1) */ \
    PH_STD(;, MFQ_FULL(1, 1, Ar1, Bc1), ;) \
    /* ph4: q(1,0); stage B(T+2)h0; gate */ \
    PH_STD({ if (SF) { STG_B((T) + 2, 0) } }, MFQ_FULL(1, 0, Ar1, Bc0), G4S) \
    /* ph5: tile T+1 q(0,0); stage A(T+2) both halves; tail-RD Bc1 */ \
    PH_HEAVY({ if (SF) { STG_A((T) + 2, 0) STG_A((T) + 2, 1) } }, 16384, \
             RD_B(Bc1, 16384, 1)) \
    /* ph6: q(0,1); stage B(T+2)h1; tail-RD Ar1 */ \
    PH_STD({ if (SF) { STG_B((T) + 2, 1) } }, MFQ_FULL(0, 1, Ar0, Bc1), \
           RD_A_LO(Ar1, 16384, 1) RD_A_HI(Ar1, 16384, 1)) \
    /* ph7: q(1,1) */ \
    PH_STD(;, MFQ_FULL(1, 1, Ar1, Bc1), ;) \
    /* ph8: q(1,0); stage B(T+3)h0; gate */ \
    PH_STD({ if (SF) { STG_B((T) + 3, 0) } }, MFQ_FULL(1, 0, Ar1, Bc0), G8S) \
}

template<int NTK>   // K-tiles of 64 per split-K block (even)
__global__ __launch_bounds__(512, 2) void gemm_ab(
    const bf16_t* __restrict__ A,      // [rows, 9216] bf16
    const bf16_t* __restrict__ W,      // [1024, 9216] bf16
    float* __restrict__ C,             // [ksplit, rows, 1024] f32 partials
    int mmask, int mshift, int rows) {
    __shared__ __align__(16) bf16_t lds[65536];    // 128 KB
    bf16_t* __restrict__ ldsA = lds;
    bf16_t* __restrict__ ldsB = lds + 32768;

    const int tid = threadIdx.x;
    const int l = tid & 63, wv = tid >> 6;
    const int wm = wv >> 2, wn = wv & 3;           // 2M x 4N waves, 128x64 each

    // XCD-aware swizzle (grid always divisible by 8)
    const int chunk = gridDim.x >> 3;
    const int bid = blockIdx.x;
    const int wg = (bid & 7) * chunk + (bid >> 3);
    const int bm = wg & mmask;
    const int bn = (wg >> mshift) & 3;
    const int ks = wg >> (mshift + 2);
    const int row0 = bm << 8, col0 = bn << 8;
    const int koff0 = ks * (NTK * 64);

    // staging geometry: thread covers local row srow of each half;
    // source k-chunk pre-swizzled so LDS stays linear-in-tid.
    const int srow = tid >> 2;
    const int schunk = (tid & 3) ^ ((srow >> 1) & 3);
    const bf16_t* __restrict__ AgS = A + (size_t)(row0 + srow) * KTOT + koff0 + schunk * 8;
    const bf16_t* __restrict__ BgS = W + (size_t)(col0 + srow) * KTOT + koff0 + schunk * 8;

    // fragment-read bases; physical chunk = (l>>4) ^ ((row>>1)&3)
    const int l15 = l & 15;
    const int pc = (l >> 4) ^ ((l15 >> 1) & 3);
    const int aOffBase = wm * 8192 + l15 * 32 + pc * 8;
    const int bOffBase = (wn >> 1) * 8192 + (wn & 1) * 2048 + l15 * 32 + pc * 8;

    f32x4 acc[8][4] = {};
    bf16x8 Ar0[4][2], Ar1[4][2], Bc0[2][2], Bc1[2][2];

    // ---- prologue: A(0),B(0) full + B(1)h0 (10 ops); publish tile 0 ----
    STG_A(0, 0) STG_A(0, 1)
    STG_B(0, 0) STG_B(0, 1)
    STG_B(1, 0)
    GATEV(2)
    BAR()

#pragma unroll 1
    for (int i = 0; i < NTK / 2 - 1; i++) {
        const int T = 2 * i;
        ITER8(T, 1, GATEV(2), GATEV(2))
    }
    // tail iter (tiles NTK-2, NTK-1): only A/B(NTK-1) completions; drain all
    ITER8(NTK - 2, 0, GATEV(0), ;)

    float* __restrict__ Cp = C + (size_t)ks * rows * DIM;
    const int r0 = row0 + wm * 128 + (l >> 4) * 4;
    const int c0 = col0 + wn * 64 + l15;
#pragma unroll
    for (int i = 0; i < 8; i++)
#pragma unroll
        for (int j = 0; j < 4; j++)
#pragma unroll
            for (int r = 0; r < 4; r++)
                Cp[(size_t)(r0 + i * 16 + r) * DIM + c0 + j * 16] = acc[i][j][r];
}

// ---------- LN + PReLU over summed partials -> next-layer A ----------
__global__ void ln_mid_A(const float* __restrict__ h, int rows, int ksplit,
                         const float* __restrict__ g_ln, const float* __restrict__ b_ln,
                         const float* __restrict__ pa, bf16_t* __restrict__ A,
                         const float* __restrict__ gp) {
    const int tid = threadIdx.x;
    const int w = tid >> 6, l = tid & 63;
    const float a = pa[0];
    const float g0 = gp[0];
    const float invh = 1.0f / (gp[1] - gp[0]);
    __shared__ float rs[4], rq[4];
    for (int row = blockIdx.x; row < rows; row += gridDim.x) {
        f32x4 v = {0.0f, 0.0f, 0.0f, 0.0f};
        for (int ks = 0; ks < ksplit; ks++)
            v += *(const f32x4*)(h + ((size_t)ks * rows + row) * DIM + tid * 4);
        float s = v[0] + v[1] + v[2] + v[3];
        float q = v[0] * v[0] + v[1] * v[1] + v[2] * v[2] + v[3] * v[3];
#pragma unroll
        for (int o = 32; o > 0; o >>= 1) { s += __shfl_xor(s, o); q += __shfl_xor(q, o); }
        if (l == 0) { rs[w] = s; rq[w] = q; }
        __syncthreads();
        s = rs[0] + rs[1] + rs[2] + rs[3];
        q = rq[0] + rq[1] + rq[2] + rq[3];
        __syncthreads();
        float mean = s * (1.0f / DIM);
        float var = q * (1.0f / DIM) - mean * mean;
        float rstd = rsqrtf(var + LN_EPS);
        bf16_t* Ar = A + (size_t)row * KTOT;
        bf16x4 ge;
#pragma unroll
        for (int c = 0; c < 4; c++) {
            int col = tid * 4 + c;
            float yv = (v[c] - mean) * rstd * g_ln[col] + b_ln[col];
            yv = (yv >= 0.0f) ? yv : a * yv;
            ge[c] = (bf16_t)gelu_exact(yv);
            uint64_t lo, hi;
            union { uint64_t u[2]; uint4 qv; } o;
            spline8(yv, g0, invh, lo, hi);
            o.u[0] = lo; o.u[1] = hi;
            *(uint4*)(Ar + DIM + (size_t)col * NCOEF) = o.qv;
        }
        *(bf16x4*)(Ar + tid * 4) = ge;
    }
}

// ---------- final LN + PReLU -> f32 out ----------
__global__ void ln_out(const float* __restrict__ h, int rows, int ksplit,
                       const float* __restrict__ g_ln, const float* __restrict__ b_ln,
                       const float* __restrict__ pa, float* __restrict__ out) {
    const int tid = threadIdx.x;
    const int w = tid >> 6, l = tid & 63;
    const float a = pa[0];
    __shared__ float rs[4], rq[4];
    for (int row = blockIdx.x; row < rows; row += gridDim.x) {
        f32x4 v = {0.0f, 0.0f, 0.0f, 0.0f};
        for (int ks = 0; ks < ksplit; ks++)
            v += *(const f32x4*)(h + ((size_t)ks * rows + row) * DIM + tid * 4);
        float s = v[0] + v[1] + v[2] + v[3];
        float q = v[0] * v[0] + v[1] * v[1] + v[2] * v[2] + v[3] * v[3];
#pragma unroll
        for (int o = 32; o > 0; o >>= 1) { s += __shfl_xor(s, o); q += __shfl_xor(q, o); }
        if (l == 0) { rs[w] = s; rq[w] = q; }
        __syncthreads();
        s = rs[0] + rs[1] + rs[2] + rs[3];
        q = rq[0] + rq[1] + rq[2] + rq[3];
        __syncthreads();
        float mean = s * (1.0f / DIM);
        float var = q * (1.0f / DIM) - mean * mean;
        float rstd = rsqrtf(var + LN_EPS);
        f32x4 o4;
#pragma unroll
        for (int c = 0; c < 4; c++) {
            int col = tid * 4 + c;
            float yv = (v[c] - mean) * rstd * g_ln[col] + b_ln[col];
            o4[c] = (yv >= 0.0f) ? yv : a * yv;
        }
        *(f32x4*)(out + (size_t)row * DIM + tid * 4) = o4;
    }
}

// ---------- launch ----------
extern "C" void kernel_launch(void* const* d_in, const int* in_sizes, int n_in,
                              void* d_out, int out_size, void* d_ws, size_t ws_size,
                              hipStream_t stream) {
    const float* x    = (const float*)d_in[0];
    const float* bw   = (const float*)d_in[1];
    const float* sw   = (const float*)d_in[2];
    const float* ln_g = (const float*)d_in[3];
    const float* ln_b = (const float*)d_in[4];
    const float* pa   = (const float*)d_in[5];
    const float* gridK = (const float*)d_in[6];
    float* out = (float*)d_out;

    const size_t wbytes = (size_t)2 * DIM * KTOT * sizeof(bf16_t);   // 37.75 MB
    int R = 8192, ksplit = 2;
    for (;;) {
        size_t need = wbytes + (size_t)R * KTOT * 2 + (size_t)ksplit * R * DIM * 4;
        if (need <= ws_size || R == 512) break;
        R >>= 1;
        int mt = R / 256;
        ksplit = (mt >= 32) ? 2 : (mt >= 16) ? 4 : 8;
    }
    int mtiles = R / 256;
    int mshift = 0; while ((1 << mshift) < mtiles) mshift++;
    int mmask = mtiles - 1;
    int grid = mtiles * 4 * ksplit;
    int lng = (R >= 2048) ? 2048 : R;

    char* wsc = (char*)d_ws;
    bf16_t* Wbuf = (bf16_t*)wsc;
    bf16_t* Abuf = (bf16_t*)(wsc + wbytes);
    float*  hbuf = (float*)(wsc + wbytes + (size_t)R * KTOT * 2);

    pack_w<<<(2 * DIM * DIM) / 256, 256, 0, stream>>>(bw, sw, Wbuf);

    auto launch_gemm = [&](const bf16_t* Wl, hipStream_t st) {
        if (ksplit == 2)
            gemm_ab<72><<<grid, 512, 0, st>>>(Abuf, Wl, hbuf, mmask, mshift, R);
        else if (ksplit == 4)
            gemm_ab<36><<<grid, 512, 0, st>>>(Abuf, Wl, hbuf, mmask, mshift, R);
        else
            gemm_ab<18><<<grid, 512, 0, st>>>(Abuf, Wl, hbuf, mmask, mshift, R);
    };

    const int nslab = BATCH / R;
    for (int sidx = 0; sidx < nslab; sidx++) {
        const size_t row0 = (size_t)sidx * R;
        const float* x0 = x + row0 * DIM;
        // layer 0
        prep_A<<<lng, 256, 0, stream>>>(x0, Abuf, gridK, R);
        launch_gemm(Wbuf, stream);
        ln_mid_A<<<lng, 256, 0, stream>>>(hbuf, R, ksplit, ln_g, ln_b, pa,
                                          Abuf, gridK + DIM * NKNOT);
        // layer 1
        launch_gemm(Wbuf + (size_t)DIM * KTOT, stream);
        ln_out<<<lng, 256, 0, stream>>>(hbuf, R, ksplit, ln_g + DIM, ln_b + DIM,
                                        pa + 1, out + row0 * DIM);
    }
}